// Round 8
// baseline (9486.378 us; speedup 1.0000x reference)
//
#include <hip/hip_runtime.h>
#include <hip/hip_bf16.h>
#include <cstdint>

#define T_TOK 32768
#define DIMD  1024
#define HID   2048
#define HSH   1024
#define NE    4

typedef __attribute__((ext_vector_type(8))) short short8;
typedef __attribute__((ext_vector_type(4))) float f32x4;

typedef const __attribute__((address_space(1))) void* gas_ptr;
typedef __attribute__((address_space(3))) void* las_ptr;

__device__ __forceinline__ void load_lds16(const void* g, void* l) {
  __builtin_amdgcn_global_load_lds((gas_ptr)g, (las_ptr)l, 16, 0, 0);
}

__device__ __forceinline__ unsigned short bf16r(float f) {
  union { float f; uint32_t u; } c; c.f = f;
  uint32_t u = c.u;
  uint32_t r = (u + 0x7FFFu + ((u >> 16) & 1u)) >> 16;
  return (unsigned short)r;
}

__device__ __forceinline__ float bf2f(unsigned short u) {
  union { uint32_t u; float f; } c; c.u = ((uint32_t)u) << 16; return c.f;
}

// ---------------- transpose fp32 [R][C] -> bf16 [C][R] ----------------
template <int TMODE>
__global__ __launch_bounds__(256) void transpose_bf16_kernel(
    const float* __restrict__ src, unsigned short* __restrict__ dst,
    int R, int C, long srcBS, long dstBS) {
  __shared__ float tile[32][33];
  const float* s = src + (long)blockIdx.z * srcBS;
  unsigned short* d = dst + (long)blockIdx.z * dstBS;
  int c0 = blockIdx.x * 32, r0 = blockIdx.y * 32;
  int tx = threadIdx.x, ty = threadIdx.y;
#pragma unroll
  for (int i = 0; i < 4; i++)
    tile[ty + i * 8][tx] = s[(long)(r0 + ty + i * 8) * C + c0 + tx];
  __syncthreads();
#pragma unroll
  for (int i = 0; i < 4; i++) {
    int c = c0 + ty + i * 8;
    int orow = (TMODE == 0) ? c : (((c >> 6) << 7) + (c & 63) + (TMODE == 2 ? 64 : 0));
    d[(long)orow * R + r0 + tx] = bf16r(tile[tx][ty + i * 8]);
  }
}

// ---------------- gating + x cast, block-aggregated list build ----------------
__global__ __launch_bounds__(256) void gating_cast_kernel(
    const float* __restrict__ x, const float* __restrict__ gw,
    unsigned short* __restrict__ xb,
    int* __restrict__ list, float* __restrict__ cw, int* __restrict__ cnt) {
  __shared__ int   se[128];
  __shared__ float sw[128];
  __shared__ int   sloc[128];
  __shared__ int   sbase[NE];
  const int lane = threadIdx.x & 63;
  const int wid = threadIdx.x >> 6;
  const int tb = blockIdx.x * 64;

  for (int j = 0; j < 16; j++) {
    const int tl = wid * 16 + j;
    const long t = tb + tl;
    const float4* xp = (const float4*)(x + t * DIMD);
    double acc[NE] = {0.0, 0.0, 0.0, 0.0};
    float4 xv[4];
#pragma unroll
    for (int i = 0; i < 4; i++) {
      xv[i] = xp[i * 64 + lane];
#pragma unroll
      for (int e = 0; e < NE; e++) {
        float4 gv = ((const float4*)(gw + e * DIMD))[i * 64 + lane];
        acc[e] += (double)xv[i].x * gv.x + (double)xv[i].y * gv.y +
                  (double)xv[i].z * gv.z + (double)xv[i].w * gv.w;
      }
    }
    ushort4* xbp = (ushort4*)(xb + t * DIMD);
#pragma unroll
    for (int i = 0; i < 4; i++) {
      ushort4 o;
      o.x = bf16r(xv[i].x); o.y = bf16r(xv[i].y);
      o.z = bf16r(xv[i].z); o.w = bf16r(xv[i].w);
      xbp[i * 64 + lane] = o;
    }
#pragma unroll
    for (int e = 0; e < NE; e++)
#pragma unroll
      for (int s = 32; s > 0; s >>= 1) acc[e] += __shfl_xor(acc[e], s, 64);
    if (lane == 0) {
      double m = acc[0];
      for (int e = 1; e < NE; e++) if (acc[e] > m) m = acc[e];
      double p[NE]; double s = 0.0;
      for (int e = 0; e < NE; e++) { p[e] = exp(acc[e] - m); s += p[e]; }
      int e0 = 0;
      for (int e = 1; e < NE; e++) if (p[e] > p[e0]) e0 = e;
      int e1 = (e0 == 0) ? 1 : 0;
      for (int e = 0; e < NE; e++) { if (e == e0) continue; if (p[e] > p[e1]) e1 = e; }
      se[tl * 2]     = e0; sw[tl * 2]     = (float)(p[e0] / s);
      se[tl * 2 + 1] = e1; sw[tl * 2 + 1] = (float)(p[e1] / s);
    }
  }
  __syncthreads();
  const int tid = threadIdx.x;
  if (tid < NE) {
    int c = 0;
    for (int s = 0; s < 128; s++)
      if (se[s] == tid) sloc[s] = c++;
    sbase[tid] = atomicAdd(&cnt[tid], c);
  }
  __syncthreads();
  if (tid < 128) {
    int e = se[tid];
    int pos = sbase[e] + sloc[tid];
    list[e * T_TOK + pos] = ((tb + (tid >> 1)) << 1) | (tid & 1);
    cw[tb * 2 + tid] = sw[tid];
  }
}

// ---------------- 256x256x32 8-wave GEMM, 4-phase schedule, 2 wgs/CU ----------------
// r8: BK 64->32, LDS 128->64 KB so TWO wgs co-reside per CU (launch_bounds
// (512,4)); cross-wg overlap fills barrier/wait bubbles (m114 mechanism).
// Same r7 supertile/XCD map (sx fixed per XCD, sy strided for M-prune balance).
// LDS buf = 32KB: A[256][32] @0, B[256][32] @16384; 2 bufs.
// Swizzle (64B rows): phys chunk = l4 ^ ((row>>1)&3) -> 64 lanes spread
// 8-per-(parity,chunk)-slot over all 32 banks (b128 conflict-free optimum).
// Staging: 1 load/thread/half; src chunk cs = (tid&3)^((tid>>3)&3), linear dest.
// Freed-region 2-ahead staging: P1 stages B1(t+1)->buf^1; P2/P3/P4 stage
// A0/B0/A1(t+2)->buf (regions freed by P1/P1/P3). vmcnt(3) at P4 => t+1 resident.
template <int EPI, int AMODE>
__global__ __launch_bounds__(512, 4) void gemm256_kernel(
    const unsigned short* __restrict__ A, const unsigned short* __restrict__ Bt,
    void* __restrict__ outp, const int* __restrict__ list,
    const int* __restrict__ cntp, int K, int OutW) {
  extern __shared__ char ldsb[];  // 65536 bytes
  const int tid = threadIdx.x, lane = tid & 63;
  const int wid = tid >> 6;
  const int wm = wid >> 2, wn = wid & 3;
  const int l15 = lane & 15, l4 = lane >> 4;

  const int gx = gridDim.x;
  const int orig = blockIdx.y * gx + blockIdx.x;
  const int xcd = orig & 7, loc = orig >> 3;
  const int s = (loc >> 5) * 8 + xcd, r = loc & 31;
  const int scols = gx >> 2;
  const int sx = s % scols, sy = s / scols;
  const int n0 = (sx * 4 + (r & 3)) * 256;
  const int m0 = (sy * 8 + (r >> 2)) * 256;

  int M = 0x7fffffff;
  if (AMODE != 0) {
    M = *cntp;
    if (m0 >= M) return;
  }

  // staging pointers: thread covers row j*128 + (tid>>2), dest chunk tid&3,
  // source k-chunk = (tid&3) ^ ((tid>>3)&3)  (row>>1 & 3 of row-in-half)
  const unsigned short* pA[2];
  const unsigned short* pB[2];
  {
    const int rb = tid >> 2;
    const int cs = (tid & 3) ^ ((tid >> 3) & 3);
#pragma unroll
    for (int j = 0; j < 2; j++) {
      int rr = j * 128 + rb;
      int arow = m0 + rr;
      long ga;
      if (AMODE == 1)      ga = list[arow < M ? arow : M - 1] >> 1;
      else if (AMODE == 2) ga = (arow < M ? arow : M - 1);
      else                 ga = arow;
      pA[j] = A + ga * (long)K + cs * 8;
      pB[j] = Bt + (long)(n0 + rr) * K + cs * 8;
    }
  }

  auto stageA = [&](int buf, int half, int koff) {
    load_lds16(pA[half] + koff, ldsb + buf * 32768 + half * 8192 + tid * 16);
  };
  auto stageB = [&](int buf, int half, int koff) {
    load_lds16(pB[half] + koff, ldsb + buf * 32768 + 16384 + half * 8192 + tid * 16);
  };

  // fragment read bases: row = (wm|wn)*16 + l15 (+fm*32 / +fn*64)
  const int ra = wm * 16 + l15;
  const int abase = ra * 64 + ((l4 ^ ((ra >> 1) & 3)) * 16);
  const int rbb = wn * 16 + l15;
  const int bbase = 16384 + rbb * 64 + ((l4 ^ ((rbb >> 1) & 3)) * 16);

  f32x4 acc[8][4] = {};
  const int nt = K >> 5;

  // prologue: t0 {A0,B0,A1,B1} + t1 {A0,B0,A1}  (queue order = steady state)
  stageA(0, 0, 0); stageB(0, 0, 0); stageA(0, 1, 0); stageB(0, 1, 0);
  if (nt > 1) { stageA(1, 0, 32); stageB(1, 0, 32); stageA(1, 1, 32); }
  if (nt > 1) asm volatile("s_waitcnt vmcnt(3)" ::: "memory");
  else        asm volatile("s_waitcnt vmcnt(0)" ::: "memory");
  __builtin_amdgcn_sched_barrier(0);
  __builtin_amdgcn_s_barrier();

  for (int kt = 0; kt < nt; ++kt) {
    const int buf = kt & 1;
    const char* Lb = ldsb + buf * 32768;
    const int ko2 = (kt + 2) * 32;
    short8 afL[4], afH[4], bfL[2], bfH[2];

    // ---------- P1: Q1 (fmL x fnL): 6 ds_read | stage B1(t+1) ----------
#pragma unroll
    for (int fm = 0; fm < 4; fm++) afL[fm] = *(const short8*)(Lb + abase + fm * 2048);
#pragma unroll
    for (int fn = 0; fn < 2; fn++) bfL[fn] = *(const short8*)(Lb + bbase + fn * 4096);
    if (kt + 1 < nt) stageB(buf ^ 1, 1, (kt + 1) * 32);
    __builtin_amdgcn_s_barrier();
    asm volatile("s_waitcnt lgkmcnt(0)" ::: "memory");
    __builtin_amdgcn_sched_barrier(0);
    __builtin_amdgcn_s_setprio(1);
#pragma unroll
    for (int fm = 0; fm < 4; fm++)
#pragma unroll
      for (int fn = 0; fn < 2; fn++)
        acc[fm][fn] = __builtin_amdgcn_mfma_f32_16x16x32_bf16(afL[fm], bfL[fn], acc[fm][fn], 0, 0, 0);
    __builtin_amdgcn_s_setprio(0);
    __builtin_amdgcn_s_barrier();

    // ---------- P2: Q2 (fmL x fnH): 2 ds_read | stage A0(t+2) ----------
#pragma unroll
    for (int fn = 0; fn < 2; fn++) bfH[fn] = *(const short8*)(Lb + bbase + (2 + fn) * 4096);
    if (kt + 2 < nt) stageA(buf, 0, ko2);
    __builtin_amdgcn_s_barrier();
    asm volatile("s_waitcnt lgkmcnt(0)" ::: "memory");
    __builtin_amdgcn_sched_barrier(0);
    __builtin_amdgcn_s_setprio(1);
#pragma unroll
    for (int fm = 0; fm < 4; fm++)
#pragma unroll
      for (int fn = 0; fn < 2; fn++)
        acc[fm][2 + fn] = __builtin_amdgcn_mfma_f32_16x16x32_bf16(afL[fm], bfH[fn], acc[fm][2 + fn], 0, 0, 0);
    __builtin_amdgcn_s_setprio(0);
    __builtin_amdgcn_s_barrier();

    // ---------- P3: Q3 (fmH x fnL): 4 ds_read | stage B0(t+2) ----------
#pragma unroll
    for (int fm = 0; fm < 4; fm++) afH[fm] = *(const short8*)(Lb + abase + (4 + fm) * 2048);
    if (kt + 2 < nt) stageB(buf, 0, ko2);
    __builtin_amdgcn_s_barrier();
    asm volatile("s_waitcnt lgkmcnt(0)" ::: "memory");
    __builtin_amdgcn_sched_barrier(0);
    __builtin_amdgcn_s_setprio(1);
#pragma unroll
    for (int fm = 0; fm < 4; fm++)
#pragma unroll
      for (int fn = 0; fn < 2; fn++)
        acc[4 + fm][fn] = __builtin_amdgcn_mfma_f32_16x16x32_bf16(afH[fm], bfL[fn], acc[4 + fm][fn], 0, 0, 0);
    __builtin_amdgcn_s_setprio(0);
    __builtin_amdgcn_s_barrier();

    // ---------- P4: Q4 (fmH x fnH): 0 ds_read | stage A1(t+2); vmcnt(3) ----------
    if (kt + 2 < nt) {
      stageA(buf, 1, ko2);
      asm volatile("s_waitcnt vmcnt(3)" ::: "memory");
    } else {
      asm volatile("s_waitcnt vmcnt(0)" ::: "memory");
    }
    __builtin_amdgcn_sched_barrier(0);
    __builtin_amdgcn_s_barrier();
    __builtin_amdgcn_s_setprio(1);
#pragma unroll
    for (int fm = 0; fm < 4; fm++)
#pragma unroll
      for (int fn = 0; fn < 2; fn++)
        acc[4 + fm][2 + fn] = __builtin_amdgcn_mfma_f32_16x16x32_bf16(afH[fm], bfH[fn], acc[4 + fm][2 + fn], 0, 0, 0);
    __builtin_amdgcn_s_setprio(0);
    __builtin_amdgcn_s_barrier();
  }

  if (EPI == 0) {
    unsigned short* Hout = (unsigned short*)outp;
#pragma unroll
    for (int fm = 0; fm < 8; fm++) {
      const int row0 = m0 + fm * 32 + wm * 16 + l4 * 4;
#pragma unroll
      for (int p = 0; p < 2; p++) {
        const int hcol = (n0 >> 1) + p * 64 + wn * 16 + l15;
        f32x4 c1 = acc[fm][2 * p], c3 = acc[fm][2 * p + 1];
#pragma unroll
        for (int rr = 0; rr < 4; rr++) {
          int rw = row0 + rr;
          if (AMODE == 0 || rw < M) {
            float v1 = c1[rr], v3 = c3[rr];
            float hv = (v1 / (1.0f + __expf(-v1))) * v3;
            Hout[(long)rw * OutW + hcol] = bf16r(hv);
          }
        }
      }
    }
  } else {
    unsigned short* O = (unsigned short*)outp;
#pragma unroll
    for (int fm = 0; fm < 8; fm++) {
#pragma unroll
      for (int rr = 0; rr < 4; rr++) {
        const int rw = m0 + fm * 32 + wm * 16 + l4 * 4 + rr;
        if (AMODE != 0 && rw >= M) continue;
        const long orow = (EPI == 2) ? (long)list[rw] : (long)rw;
#pragma unroll
        for (int fn = 0; fn < 4; fn++)
          O[orow * OutW + n0 + fn * 64 + wn * 16 + l15] = bf16r(acc[fm][fn][rr]);
      }
    }
  }
}

// ---------------- final combine: y = sbuf + w0*rbuf[2t] + w1*rbuf[2t+1] ----------------
__global__ __launch_bounds__(256) void combine_kernel(
    const unsigned short* __restrict__ sbuf, const unsigned short* __restrict__ rbuf,
    const float* __restrict__ cw, float* __restrict__ y) {
  const int t = blockIdx.x * 2 + (threadIdx.x >> 7);
  const int c8 = (threadIdx.x & 127) * 8;
  const float w0 = cw[t * 2], w1 = cw[t * 2 + 1];
  short8 s = *(const short8*)(sbuf + (long)t * 1024 + c8);
  short8 a = *(const short8*)(rbuf + (long)(t * 2) * 1024 + c8);
  short8 b = *(const short8*)(rbuf + (long)(t * 2 + 1) * 1024 + c8);
  float* yp = y + (long)t * 1024 + c8;
  float ov[8];
#pragma unroll
  for (int i = 0; i < 8; i++)
    ov[i] = bf2f((unsigned short)s[i]) + w0 * bf2f((unsigned short)a[i]) +
            w1 * bf2f((unsigned short)b[i]);
  *(float4*)(yp)     = make_float4(ov[0], ov[1], ov[2], ov[3]);
  *(float4*)(yp + 4) = make_float4(ov[4], ov[5], ov[6], ov[7]);
}

// ---------------- launch ----------------
extern "C" void kernel_launch(void* const* d_in, const int* in_sizes, int n_in,
                              void* d_out, int out_size, void* d_ws, size_t ws_size,
                              hipStream_t stream) {
  const float* x  = (const float*)d_in[0];
  const float* gw = (const float*)d_in[1];
  const float* W1 = (const float*)d_in[2];
  const float* W3 = (const float*)d_in[3];
  const float* W2 = (const float*)d_in[4];
  const float* Ws1 = (const float*)d_in[5];
  const float* Ws3 = (const float*)d_in[6];
  const float* Ws2 = (const float*)d_in[7];
  float* y = (float*)d_out;

  char* ws = (char*)d_ws;
  unsigned short* xb    = (unsigned short*)(ws + 0);            //  64 MB [T][1024]
  unsigned short* wt13  = (unsigned short*)(ws + 67108864L);    //  32 MB [4][4096][1024] (ilv64)
  unsigned short* wt2   = (unsigned short*)(ws + 100663296L);   //  16 MB [4][1024][2048]
  unsigned short* wts13 = (unsigned short*)(ws + 117440512L);   //   4 MB [2048][1024] (ilv64)
  unsigned short* wts2  = (unsigned short*)(ws + 121634816L);   //   2 MB [1024][1024]
  unsigned short* hbuf  = (unsigned short*)(ws + 123731968L);   // 128 MB [T][2048]
  unsigned short* rbuf  = (unsigned short*)(ws + 257949696L);   // 128 MB [2T][1024] bf16
  unsigned short* sbuf  = (unsigned short*)(ws + 392167424L);   //  64 MB [T][1024] bf16
  int*   list = (int*)(ws + 459276288L);                        // [4][T] tok*2+rank
  float* cw   = (float*)(ws + 459800576L);                      // [2T] token-indexed
  int*   cnt  = (int*)(ws + 460062720L);                        // [4]

  hipMemsetAsync(cnt, 0, 16, stream);

  transpose_bf16_kernel<1><<<dim3(64, 32, 4), dim3(32, 8), 0, stream>>>(
      W1, wt13, 1024, 2048, 1024L * 2048, 4096L * 1024);
  transpose_bf16_kernel<2><<<dim3(64, 32, 4), dim3(32, 8), 0, stream>>>(
      W3, wt13, 1024, 2048, 1024L * 2048, 4096L * 1024);
  transpose_bf16_kernel<0><<<dim3(32, 64, 4), dim3(32, 8), 0, stream>>>(
      W2, wt2, 2048, 1024, 2048L * 1024, 1024L * 2048);
  transpose_bf16_kernel<1><<<dim3(32, 32, 1), dim3(32, 8), 0, stream>>>(
      Ws1, wts13, 1024, 1024, 0, 0);
  transpose_bf16_kernel<2><<<dim3(32, 32, 1), dim3(32, 8), 0, stream>>>(
      Ws3, wts13, 1024, 1024, 0, 0);
  transpose_bf16_kernel<0><<<dim3(32, 32, 1), dim3(32, 8), 0, stream>>>(
      Ws2, wts2, 1024, 1024, 0, 0);

  gating_cast_kernel<<<T_TOK / 64, 256, 0, stream>>>(x, gw, xb, list, cw, cnt);

  // shared expert: h_s -> hbuf [T][1024]; sbuf = h_s @ Ws2 (bf16)
  gemm256_kernel<0, 0><<<dim3(8, 128), 512, 65536, stream>>>(
      xb, wts13, hbuf, nullptr, nullptr, 1024, 1024);
  gemm256_kernel<1, 0><<<dim3(4, 128), 512, 65536, stream>>>(
      hbuf, wts2, sbuf, nullptr, nullptr, 1024, 1024);

  // routed experts, sequential (hbuf reuse); ffn2 writes rbuf[tok*2+rank] (no RMW)
  for (int e = 0; e < NE; e++) {
    gemm256_kernel<0, 1><<<dim3(16, 128), 512, 65536, stream>>>(
        xb, wt13 + (long)e * 4096 * 1024, hbuf, list + e * T_TOK, cnt + e, 1024, 2048);
    gemm256_kernel<2, 2><<<dim3(4, 128), 512, 65536, stream>>>(
        hbuf, wt2 + (long)e * 1024 * 2048, rbuf, list + e * T_TOK, cnt + e, 2048, 1024);
  }

  combine_kernel<<<T_TOK / 2, 256, 0, stream>>>(sbuf, rbuf, cw, y);
}

// Round 10
// 1274.681 us; speedup vs baseline: 7.4422x; 7.4422x over previous
//
#include <hip/hip_runtime.h>
#include <hip/hip_bf16.h>
#include <cstdint>

#define T_TOK 32768
#define DIMD  1024
#define HID   2048
#define HSH   1024
#define NE    4

typedef __attribute__((ext_vector_type(8))) short short8;
typedef __attribute__((ext_vector_type(4))) float f32x4;

typedef const __attribute__((address_space(1))) void* gas_ptr;
typedef __attribute__((address_space(3))) void* las_ptr;

__device__ __forceinline__ void load_lds16(const void* g, void* l) {
  __builtin_amdgcn_global_load_lds((gas_ptr)g, (las_ptr)l, 16, 0, 0);
}

__device__ __forceinline__ unsigned short bf16r(float f) {
  union { float f; uint32_t u; } c; c.f = f;
  uint32_t u = c.u;
  uint32_t r = (u + 0x7FFFu + ((u >> 16) & 1u)) >> 16;
  return (unsigned short)r;
}

__device__ __forceinline__ float bf2f(unsigned short u) {
  union { uint32_t u; float f; } c; c.u = ((uint32_t)u) << 16; return c.f;
}

// ---------------- transpose fp32 [R][C] -> bf16 [C][R] ----------------
template <int TMODE>
__global__ __launch_bounds__(256) void transpose_bf16_kernel(
    const float* __restrict__ src, unsigned short* __restrict__ dst,
    int R, int C, long srcBS, long dstBS) {
  __shared__ float tile[32][33];
  const float* s = src + (long)blockIdx.z * srcBS;
  unsigned short* d = dst + (long)blockIdx.z * dstBS;
  int c0 = blockIdx.x * 32, r0 = blockIdx.y * 32;
  int tx = threadIdx.x, ty = threadIdx.y;
#pragma unroll
  for (int i = 0; i < 4; i++)
    tile[ty + i * 8][tx] = s[(long)(r0 + ty + i * 8) * C + c0 + tx];
  __syncthreads();
#pragma unroll
  for (int i = 0; i < 4; i++) {
    int c = c0 + ty + i * 8;
    int orow = (TMODE == 0) ? c : (((c >> 6) << 7) + (c & 63) + (TMODE == 2 ? 64 : 0));
    d[(long)orow * R + r0 + tx] = bf16r(tile[tx][ty + i * 8]);
  }
}

// ---------------- gating + x cast, block-aggregated list build ----------------
__global__ __launch_bounds__(256) void gating_cast_kernel(
    const float* __restrict__ x, const float* __restrict__ gw,
    unsigned short* __restrict__ xb,
    int* __restrict__ list, float* __restrict__ cw, int* __restrict__ cnt) {
  __shared__ int   se[128];
  __shared__ float sw[128];
  __shared__ int   sloc[128];
  __shared__ int   sbase[NE];
  const int lane = threadIdx.x & 63;
  const int wid = threadIdx.x >> 6;
  const int tb = blockIdx.x * 64;

  for (int j = 0; j < 16; j++) {
    const int tl = wid * 16 + j;
    const long t = tb + tl;
    const float4* xp = (const float4*)(x + t * DIMD);
    double acc[NE] = {0.0, 0.0, 0.0, 0.0};
    float4 xv[4];
#pragma unroll
    for (int i = 0; i < 4; i++) {
      xv[i] = xp[i * 64 + lane];
#pragma unroll
      for (int e = 0; e < NE; e++) {
        float4 gv = ((const float4*)(gw + e * DIMD))[i * 64 + lane];
        acc[e] += (double)xv[i].x * gv.x + (double)xv[i].y * gv.y +
                  (double)xv[i].z * gv.z + (double)xv[i].w * gv.w;
      }
    }
    ushort4* xbp = (ushort4*)(xb + t * DIMD);
#pragma unroll
    for (int i = 0; i < 4; i++) {
      ushort4 o;
      o.x = bf16r(xv[i].x); o.y = bf16r(xv[i].y);
      o.z = bf16r(xv[i].z); o.w = bf16r(xv[i].w);
      xbp[i * 64 + lane] = o;
    }
#pragma unroll
    for (int e = 0; e < NE; e++)
#pragma unroll
      for (int s = 32; s > 0; s >>= 1) acc[e] += __shfl_xor(acc[e], s, 64);
    if (lane == 0) {
      double m = acc[0];
      for (int e = 1; e < NE; e++) if (acc[e] > m) m = acc[e];
      double p[NE]; double s = 0.0;
      for (int e = 0; e < NE; e++) { p[e] = exp(acc[e] - m); s += p[e]; }
      int e0 = 0;
      for (int e = 1; e < NE; e++) if (p[e] > p[e0]) e0 = e;
      int e1 = (e0 == 0) ? 1 : 0;
      for (int e = 0; e < NE; e++) { if (e == e0) continue; if (p[e] > p[e1]) e1 = e; }
      se[tl * 2]     = e0; sw[tl * 2]     = (float)(p[e0] / s);
      se[tl * 2 + 1] = e1; sw[tl * 2 + 1] = (float)(p[e1] / s);
    }
  }
  __syncthreads();
  const int tid = threadIdx.x;
  if (tid < NE) {
    int c = 0;
    for (int s = 0; s < 128; s++)
      if (se[s] == tid) sloc[s] = c++;
    sbase[tid] = atomicAdd(&cnt[tid], c);
  }
  __syncthreads();
  if (tid < 128) {
    int e = se[tid];
    int pos = sbase[e] + sloc[tid];
    list[e * T_TOK + pos] = ((tb + (tid >> 1)) << 1) | (tid & 1);
    cw[tb * 2 + tid] = sw[tid];
  }
}

// ---------------- expert row-offset prefix (4 adds) ----------------
__global__ void prefix_kernel(const int* __restrict__ cnt, int* __restrict__ prefix) {
  if (threadIdx.x == 0) {
    int a = 0;
    for (int e = 0; e < NE; e++) { prefix[e] = a; a += cnt[e]; }
  }
}

// ---------------- 256x256x64 8-wave GEMM, 8-phase schedule (r7-verified loop) ----------------
// Multi-expert: blockIdx.z = expert e; M = cnt[e], per-expert packed rows at
// prefix[e] in hbuf; list/Bt offset by e. Supertile/XCD map per z-slice
// (sx fixed per XCD, sy strided -> M-prune balanced). Bijective iff nwg%256==0.
// EPI 0: SwiGLU bf16 -> Hout[(base+rw)*OutW]    (Bt 64-col-ilv W1/W3)
//     1: f32 dense   -> Y[rw*OutW]              (shared ffn2 writes y directly)
//     2: bf16 scatter-> O[listE[rw]*OutW]       (routed ffn2 -> rbuf, no RMW)
// AMODE 0: dense A rows | 1: A row = listE[min(rw,M-1)]>>1 | 2: A row = base+min(rw,M-1)
template <int EPI, int AMODE>
__global__ __launch_bounds__(512, 2) void gemm256_kernel(
    const unsigned short* __restrict__ A, const unsigned short* __restrict__ Bt,
    void* __restrict__ outp, const int* __restrict__ list,
    const int* __restrict__ cnt, const int* __restrict__ prefix,
    int K, int OutW, long BtStride) {
  extern __shared__ char ldsb[];  // 131072 bytes
  const int tid = threadIdx.x, lane = tid & 63;
  const int wid = tid >> 6;
  const int wm = wid >> 2, wn = wid & 3;
  const int l15 = lane & 15, l4 = lane >> 4;
  const int e = blockIdx.z;

  const int gx = gridDim.x;
  const int orig = blockIdx.y * gx + blockIdx.x;
  const int xcd = orig & 7, loc = orig >> 3;
  const int s = (loc >> 5) * 8 + xcd, r = loc & 31;
  const int scols = gx >> 2;
  const int sx = s % scols, sy = s / scols;
  const int n0 = (sx * 4 + (r & 3)) * 256;
  const int m0 = (sy * 8 + (r >> 2)) * 256;

  int M = 0x7fffffff;
  int base = 0;
  const int* listE = list;
  if (AMODE != 0) {
    M = cnt[e];
    if (m0 >= M) return;
    base = prefix[e];
    listE = list + e * T_TOK;
  }
  const unsigned short* BtE = Bt + (long)e * BtStride;

  const unsigned short* pA[4];
  const unsigned short* pB[4];
  {
    const int rb = tid >> 3;
    const int cs = (tid & 7) ^ (rb & 7);
#pragma unroll
    for (int j = 0; j < 4; j++) {
      int rr = j * 64 + rb;
      int arow = m0 + rr;
      long ga;
      if (AMODE == 1)      ga = listE[arow < M ? arow : M - 1] >> 1;
      else if (AMODE == 2) ga = base + (arow < M ? arow : M - 1);
      else                 ga = arow;
      pA[j] = A + ga * (long)K + cs * 8;
      pB[j] = BtE + (long)(n0 + rr) * K + cs * 8;
    }
  }

  auto stageA = [&](int buf, int half, int koff) {
    char* d = ldsb + buf * 65536 + half * 16384 + tid * 16;
    load_lds16(pA[half * 2 + 0] + koff, d);
    load_lds16(pA[half * 2 + 1] + koff, d + 8192);
  };
  auto stageB = [&](int buf, int half, int koff) {
    char* d = ldsb + buf * 65536 + 32768 + half * 16384 + tid * 16;
    load_lds16(pB[half * 2 + 0] + koff, d);
    load_lds16(pB[half * 2 + 1] + koff, d + 8192);
  };

  const int sw8 = l15 & 7;
  const int abase = (wm * 16 + l15) * 128 + ((l4 ^ sw8) * 16);
  const int bbase = 32768 + (wn * 16 + l15) * 128 + ((l4 ^ sw8) * 16);

  f32x4 acc[8][4] = {};
  const int nt = K >> 6;

  stageA(0, 0, 0); stageA(0, 1, 0); stageB(0, 0, 0); stageB(0, 1, 0);
  if (nt > 1) { stageA(1, 0, 64); stageB(1, 0, 64); stageA(1, 1, 64); }
  if (nt > 1) asm volatile("s_waitcnt vmcnt(6)" ::: "memory");
  else        asm volatile("s_waitcnt vmcnt(0)" ::: "memory");
  __builtin_amdgcn_sched_barrier(0);
  __builtin_amdgcn_s_barrier();

  for (int kt = 0; kt < nt; ++kt) {
    const int buf = kt & 1;
    const char* Lb = ldsb + buf * 65536;
    const int ko2 = (kt + 2) * 64;
    short8 afL[2][4], afH[2][4], bfL[2][2], bfH[2][2];

    // ---------- P1: Q1 (fmL x fnL) ----------
#pragma unroll
    for (int ks = 0; ks < 2; ks++) {
#pragma unroll
      for (int fm = 0; fm < 4; fm++)
        afL[ks][fm] = *(const short8*)(Lb + ((abase + fm * 4096) ^ (ks << 6)));
#pragma unroll
      for (int fn = 0; fn < 2; fn++)
        bfL[ks][fn] = *(const short8*)(Lb + ((bbase + fn * 8192) ^ (ks << 6)));
    }
    if (kt + 1 < nt) stageB(buf ^ 1, 1, (kt + 1) * 64);
    __builtin_amdgcn_s_barrier();
    asm volatile("s_waitcnt lgkmcnt(0)" ::: "memory");
    __builtin_amdgcn_sched_barrier(0);
    __builtin_amdgcn_s_setprio(1);
#pragma unroll
    for (int ks = 0; ks < 2; ks++)
#pragma unroll
      for (int fm = 0; fm < 4; fm++)
#pragma unroll
        for (int fn = 0; fn < 2; fn++)
          acc[fm][fn] = __builtin_amdgcn_mfma_f32_16x16x32_bf16(afL[ks][fm], bfL[ks][fn], acc[fm][fn], 0, 0, 0);
    __builtin_amdgcn_s_setprio(0);
    __builtin_amdgcn_s_barrier();

    // ---------- P2: Q2 (fmL x fnH) ----------
#pragma unroll
    for (int ks = 0; ks < 2; ks++)
#pragma unroll
      for (int fn = 0; fn < 2; fn++)
        bfH[ks][fn] = *(const short8*)(Lb + ((bbase + (2 + fn) * 8192) ^ (ks << 6)));
    if (kt + 2 < nt) stageA(buf, 0, ko2);
    __builtin_amdgcn_s_barrier();
    asm volatile("s_waitcnt lgkmcnt(0)" ::: "memory");
    __builtin_amdgcn_sched_barrier(0);
    __builtin_amdgcn_s_setprio(1);
#pragma unroll
    for (int ks = 0; ks < 2; ks++)
#pragma unroll
      for (int fm = 0; fm < 4; fm++)
#pragma unroll
        for (int fn = 0; fn < 2; fn++)
          acc[fm][2 + fn] = __builtin_amdgcn_mfma_f32_16x16x32_bf16(afL[ks][fm], bfH[ks][fn], acc[fm][2 + fn], 0, 0, 0);
    __builtin_amdgcn_s_setprio(0);
    __builtin_amdgcn_s_barrier();

    // ---------- P3: Q3 (fmH x fnL) ----------
#pragma unroll
    for (int ks = 0; ks < 2; ks++)
#pragma unroll
      for (int fm = 0; fm < 4; fm++)
        afH[ks][fm] = *(const short8*)(Lb + ((abase + (4 + fm) * 4096) ^ (ks << 6)));
    if (kt + 2 < nt) stageB(buf, 0, ko2);
    __builtin_amdgcn_s_barrier();
    asm volatile("s_waitcnt lgkmcnt(0)" ::: "memory");
    __builtin_amdgcn_sched_barrier(0);
    __builtin_amdgcn_s_setprio(1);
#pragma unroll
    for (int ks = 0; ks < 2; ks++)
#pragma unroll
      for (int fm = 0; fm < 4; fm++)
#pragma unroll
        for (int fn = 0; fn < 2; fn++)
          acc[4 + fm][fn] = __builtin_amdgcn_mfma_f32_16x16x32_bf16(afH[ks][fm], bfL[ks][fn], acc[4 + fm][fn], 0, 0, 0);
    __builtin_amdgcn_s_setprio(0);
    __builtin_amdgcn_s_barrier();

    // ---------- P4: Q4 (fmH x fnH) ----------
    if (kt + 2 < nt) {
      stageA(buf, 1, ko2);
      asm volatile("s_waitcnt vmcnt(6)" ::: "memory");
    } else {
      asm volatile("s_waitcnt vmcnt(0)" ::: "memory");
    }
    __builtin_amdgcn_sched_barrier(0);
    __builtin_amdgcn_s_barrier();
    __builtin_amdgcn_s_setprio(1);
#pragma unroll
    for (int ks = 0; ks < 2; ks++)
#pragma unroll
      for (int fm = 0; fm < 4; fm++)
#pragma unroll
        for (int fn = 0; fn < 2; fn++)
          acc[4 + fm][2 + fn] = __builtin_amdgcn_mfma_f32_16x16x32_bf16(afH[ks][fm], bfH[ks][fn], acc[4 + fm][2 + fn], 0, 0, 0);
    __builtin_amdgcn_s_setprio(0);
    __builtin_amdgcn_s_barrier();
  }

  if (EPI == 0) {
    unsigned short* Hout = (unsigned short*)outp;
#pragma unroll
    for (int fm = 0; fm < 8; fm++) {
      const int row0 = m0 + fm * 32 + wm * 16 + l4 * 4;
#pragma unroll
      for (int p = 0; p < 2; p++) {
        const int hcol = (n0 >> 1) + p * 64 + wn * 16 + l15;
        f32x4 c1 = acc[fm][2 * p], c3 = acc[fm][2 * p + 1];
#pragma unroll
        for (int rr = 0; rr < 4; rr++) {
          int rw = row0 + rr;
          if (AMODE == 0 || rw < M) {
            float v1 = c1[rr], v3 = c3[rr];
            float hv = (v1 / (1.0f + __expf(-v1))) * v3;
            Hout[(long)(base + rw) * OutW + hcol] = bf16r(hv);
          }
        }
      }
    }
  } else if (EPI == 1) {
    float* Y = (float*)outp;
#pragma unroll
    for (int fm = 0; fm < 8; fm++) {
#pragma unroll
      for (int rr = 0; rr < 4; rr++) {
        const int rw = m0 + fm * 32 + wm * 16 + l4 * 4 + rr;
#pragma unroll
        for (int fn = 0; fn < 4; fn++)
          Y[(long)rw * OutW + n0 + fn * 64 + wn * 16 + l15] = acc[fm][fn][rr];
      }
    }
  } else {
    unsigned short* O = (unsigned short*)outp;
#pragma unroll
    for (int fm = 0; fm < 8; fm++) {
#pragma unroll
      for (int rr = 0; rr < 4; rr++) {
        const int rw = m0 + fm * 32 + wm * 16 + l4 * 4 + rr;
        if (rw >= M) continue;
        const long orow = (long)listE[rw];
#pragma unroll
        for (int fn = 0; fn < 4; fn++)
          O[orow * OutW + n0 + fn * 64 + wn * 16 + l15] = bf16r(acc[fm][fn][rr]);
      }
    }
  }
}

// ---------------- final combine (in place): y += w0*rbuf[2t] + w1*rbuf[2t+1] ----------------
__global__ __launch_bounds__(256) void combine_kernel(
    const unsigned short* __restrict__ rbuf, const float* __restrict__ cw,
    float* __restrict__ y) {
  const int t = blockIdx.x * 2 + (threadIdx.x >> 7);
  const int c8 = (threadIdx.x & 127) * 8;
  const float w0 = cw[t * 2], w1 = cw[t * 2 + 1];
  short8 a = *(const short8*)(rbuf + (long)(t * 2) * 1024 + c8);
  short8 b = *(const short8*)(rbuf + (long)(t * 2 + 1) * 1024 + c8);
  float* yp = y + (long)t * 1024 + c8;
  float4 y0 = *(float4*)(yp);
  float4 y1 = *(float4*)(yp + 4);
  float ov[8] = {y0.x, y0.y, y0.z, y0.w, y1.x, y1.y, y1.z, y1.w};
#pragma unroll
  for (int i = 0; i < 8; i++)
    ov[i] += w0 * bf2f((unsigned short)a[i]) + w1 * bf2f((unsigned short)b[i]);
  *(float4*)(yp)     = make_float4(ov[0], ov[1], ov[2], ov[3]);
  *(float4*)(yp + 4) = make_float4(ov[4], ov[5], ov[6], ov[7]);
}

// ---------------- launch ----------------
extern "C" void kernel_launch(void* const* d_in, const int* in_sizes, int n_in,
                              void* d_out, int out_size, void* d_ws, size_t ws_size,
                              hipStream_t stream) {
  const float* x  = (const float*)d_in[0];
  const float* gw = (const float*)d_in[1];
  const float* W1 = (const float*)d_in[2];
  const float* W3 = (const float*)d_in[3];
  const float* W2 = (const float*)d_in[4];
  const float* Ws1 = (const float*)d_in[5];
  const float* Ws3 = (const float*)d_in[6];
  const float* Ws2 = (const float*)d_in[7];
  float* y = (float*)d_out;

  // ws layout (~428 MB), with time-disjoint aliasing:
  //   rbuf [0..128M) aliases xb+wt13 (dead once routed ffn1_all completes)
  char* ws = (char*)d_ws;
  unsigned short* xb    = (unsigned short*)(ws + 0);            //  64 MB [T][1024]
  unsigned short* wt13  = (unsigned short*)(ws + 67108864L);    //  32 MB [4][4096][1024] (ilv64)
  unsigned short* rbuf  = (unsigned short*)(ws + 0);            // 128 MB [2T][1024] (aliases xb+wt13+gap)
  unsigned short* wt2   = (unsigned short*)(ws + 134217728L);   //  16 MB [4][1024][2048]
  unsigned short* wts13 = (unsigned short*)(ws + 150994944L);   //   4 MB [2048][1024] (ilv64)
  unsigned short* wts2  = (unsigned short*)(ws + 155189248L);   //   2 MB [1024][1024]
  int*   list   = (int*)(ws + 157286400L);                      // [4][T] tok*2+rank
  float* cw     = (float*)(ws + 157810688L);                    // [2T]
  int*   cnt    = (int*)(ws + 158072832L);                      // [4]
  int*   prefix = (int*)(ws + 158072896L);                      // [4]
  unsigned short* hbuf  = (unsigned short*)(ws + 159383552L);   // 256 MB [2T][2048] (packed by prefix)

  hipMemsetAsync(cnt, 0, 16, stream);

  transpose_bf16_kernel<1><<<dim3(64, 32, 4), dim3(32, 8), 0, stream>>>(
      W1, wt13, 1024, 2048, 1024L * 2048, 4096L * 1024);
  transpose_bf16_kernel<2><<<dim3(64, 32, 4), dim3(32, 8), 0, stream>>>(
      W3, wt13, 1024, 2048, 1024L * 2048, 4096L * 1024);
  transpose_bf16_kernel<0><<<dim3(32, 64, 4), dim3(32, 8), 0, stream>>>(
      W2, wt2, 2048, 1024, 2048L * 1024, 1024L * 2048);
  transpose_bf16_kernel<1><<<dim3(32, 32, 1), dim3(32, 8), 0, stream>>>(
      Ws1, wts13, 1024, 1024, 0, 0);
  transpose_bf16_kernel<2><<<dim3(32, 32, 1), dim3(32, 8), 0, stream>>>(
      Ws3, wts13, 1024, 1024, 0, 0);
  transpose_bf16_kernel<0><<<dim3(32, 32, 1), dim3(32, 8), 0, stream>>>(
      Ws2, wts2, 1024, 1024, 0, 0);

  gating_cast_kernel<<<T_TOK / 64, 256, 0, stream>>>(x, gw, xb, list, cw, cnt);
  prefix_kernel<<<1, 64, 0, stream>>>(cnt, prefix);

  // shared expert: h_s -> hbuf[0:T) width 1024; y = h_s @ Ws2 (f32 dense)
  gemm256_kernel<0, 0><<<dim3(8, 128, 1), 512, 131072, stream>>>(
      xb, wts13, hbuf, nullptr, nullptr, nullptr, 1024, 1024, 0);
  gemm256_kernel<1, 0><<<dim3(4, 128, 1), 512, 131072, stream>>>(
      hbuf, wts2, y, nullptr, nullptr, nullptr, 1024, 1024, 0);

  // routed experts, ALL in one dispatch each (z = expert); h packed at prefix[e]
  gemm256_kernel<0, 1><<<dim3(16, 128, 4), 512, 131072, stream>>>(
      xb, wt13, hbuf, list, cnt, prefix, 1024, 2048, 4096L * 1024);
  gemm256_kernel<2, 2><<<dim3(4, 128, 4), 512, 131072, stream>>>(
      hbuf, wt2, rbuf, list, cnt, prefix, 2048, 1024, 1024L * 2048);

  combine_kernel<<<T_TOK / 2, 256, 0, stream>>>(rbuf, cw, y);
}